// Round 5
// baseline (67.732 us; speedup 1.0000x reference)
//
#include <hip/hip_runtime.h>
#include <hip/hip_bf16.h>

// B=2, LQ=LKV=1024, H=8, DQK=DV=64, DQ=DK=DVIN=DOUT=512, SPAN=128, STRIDE=1
#define LQ 1024
#define NH 8
#define DHEAD 64
#define DMODEL 512
#define SPAN 128
#define MROWS 2048   // B*LQ

typedef __attribute__((ext_vector_type(8))) short   bf16x8;
typedef __attribute__((ext_vector_type(4))) float   f32x4;
typedef __attribute__((ext_vector_type(8))) unsigned short us8;

static __device__ __forceinline__ unsigned short f2bf(float f) {
    union { __hip_bfloat16 h; unsigned short u; } cv;
    cv.h = __float2bfloat16(f);
    return cv.u;
}

// ---------------------------------------------------------------------------
// Prep: transpose+cast weights: Wt[n][k] = bf16(W[k][n]), 512x512 each
// (unchanged — validated)
// ---------------------------------------------------------------------------
__global__ __launch_bounds__(256) void transposeW(
    const float* __restrict__ W0, const float* __restrict__ W1,
    const float* __restrict__ W2, const float* __restrict__ W3,
    unsigned short* __restrict__ T0, unsigned short* __restrict__ T1,
    unsigned short* __restrict__ T2, unsigned short* __restrict__ T3)
{
    const float* W = blockIdx.z == 0 ? W0 : blockIdx.z == 1 ? W1 : blockIdx.z == 2 ? W2 : W3;
    unsigned short* T = blockIdx.z == 0 ? T0 : blockIdx.z == 1 ? T1 : blockIdx.z == 2 ? T2 : T3;
    __shared__ unsigned short sT[64][72];
    int c = threadIdx.x & 63;
    int r0 = (threadIdx.x >> 6) * 16;
    int n0 = blockIdx.x * 64, k0 = blockIdx.y * 64;
    #pragma unroll
    for (int i = 0; i < 16; ++i) {
        int r = r0 + i;
        sT[c][r] = f2bf(W[(size_t)(k0 + r) * DMODEL + n0 + c]);
    }
    __syncthreads();
    #pragma unroll
    for (int i = 0; i < 16; ++i) {
        int r = r0 + i;
        T[(size_t)(n0 + r) * DMODEL + k0 + c] = sT[r][c];
    }
}

// ---------------------------------------------------------------------------
// Direct-from-L2 MFMA GEMM (no LDS, no barriers).
// C[M=2048][N=512] = A[M][K=512] @ W[K][N]; Bt = W^T bf16 [N][K].
// Wave computes 32x32 (2x2 frags of 16x16x32); block = 4 waves = 64x64 tile.
// AF32: A is f32 (converted in-register), else bf16.
// MODE 0: C f32 row-major.
// MODE 1: scatter bf16 to (B,H,LQ,64).
// MODE 2: swapped operands, write C^T bf16 to (B,H,64,LQ).
// A0/A1, C0/C1 selected by blockIdx.z (fused Q+K projections).
// ---------------------------------------------------------------------------
template<int MODE, bool AF32>
__global__ __launch_bounds__(256) void gemm_direct(
    const void* __restrict__ A0, const void* __restrict__ A1,
    const unsigned short* __restrict__ B0, const unsigned short* __restrict__ B1,
    void* __restrict__ C0, void* __restrict__ C1)
{
    const int z = blockIdx.z;
    const void* Av = z ? A1 : A0;
    const unsigned short* Bt = z ? B1 : B0;
    void* Cv = z ? C1 : C0;

    const int lane = threadIdx.x & 63;
    const int w = threadIdx.x >> 6;
    const int wm = w >> 1, wn = w & 1;
    const int m0 = blockIdx.y * 64;
    const int n0 = blockIdx.x * 64;
    const int frow = lane & 15;
    const int fkg  = lane >> 4;

    f32x4 acc[2][2];
    #pragma unroll
    for (int i = 0; i < 2; ++i)
        #pragma unroll
        for (int j = 0; j < 2; ++j)
            acc[i][j] = f32x4{0.f, 0.f, 0.f, 0.f};

    const int ar0 = m0 + wm * 32 + frow;        // a-frag rows (m-dim)
    const int br0 = n0 + wn * 32 + frow;        // b-frag rows (n-dim)

    #pragma unroll
    for (int ks = 0; ks < 16; ++ks) {
        const int k = ks * 32 + fkg * 8;
        bf16x8 af[2], bfr[2];
        if constexpr (AF32) {
            const float* Af = (const float*)Av;
            #pragma unroll
            for (int i = 0; i < 2; ++i) {
                const float4* p = (const float4*)(Af + (size_t)(ar0 + i * 16) * DMODEL + k);
                float4 lo = p[0], hi = p[1];
                bf16x8 t;
                t[0] = (short)f2bf(lo.x); t[1] = (short)f2bf(lo.y);
                t[2] = (short)f2bf(lo.z); t[3] = (short)f2bf(lo.w);
                t[4] = (short)f2bf(hi.x); t[5] = (short)f2bf(hi.y);
                t[6] = (short)f2bf(hi.z); t[7] = (short)f2bf(hi.w);
                af[i] = t;
            }
        } else {
            const unsigned short* Ab = (const unsigned short*)Av;
            #pragma unroll
            for (int i = 0; i < 2; ++i)
                af[i] = *(const bf16x8*)&Ab[(size_t)(ar0 + i * 16) * DMODEL + k];
        }
        #pragma unroll
        for (int j = 0; j < 2; ++j)
            bfr[j] = *(const bf16x8*)&Bt[(size_t)(br0 + j * 16) * DMODEL + k];

        #pragma unroll
        for (int i = 0; i < 2; ++i)
            #pragma unroll
            for (int j = 0; j < 2; ++j) {
                if constexpr (MODE == 2)
                    acc[i][j] = __builtin_amdgcn_mfma_f32_16x16x32_bf16(bfr[i], af[j], acc[i][j], 0, 0, 0);
                else
                    acc[i][j] = __builtin_amdgcn_mfma_f32_16x16x32_bf16(af[i], bfr[j], acc[i][j], 0, 0, 0);
            }
    }

    // C/D layout: col = lane&15, row = (lane>>4)*4 + r   [m89-verified]
    #pragma unroll
    for (int i = 0; i < 2; ++i) {
        #pragma unroll
        for (int j = 0; j < 2; ++j) {
            #pragma unroll
            for (int r = 0; r < 4; ++r) {
                if constexpr (MODE == 2) {
                    // acc rows = n-dim (i), cols = m-dim (j)
                    int n = n0 + wn * 32 + i * 16 + (lane >> 4) * 4 + r;
                    int m = m0 + wm * 32 + j * 16 + (lane & 15);
                    int b = m >> 10, jq = m & 1023, h = n >> 6, d = n & 63;
                    ((unsigned short*)Cv)[(((size_t)(b * NH + h) * DHEAD) + d) * LQ + jq] = f2bf(acc[i][j][r]);
                } else {
                    int m = m0 + wm * 32 + i * 16 + (lane >> 4) * 4 + r;
                    int n = n0 + wn * 32 + j * 16 + (lane & 15);
                    if constexpr (MODE == 1) {
                        int b = m >> 10, jq = m & 1023, h = n >> 6, d = n & 63;
                        ((unsigned short*)Cv)[(((size_t)(b * NH + h) * LQ) + jq) * DHEAD + d] = f2bf(acc[i][j][r]);
                    } else {
                        ((float*)Cv)[(size_t)m * DMODEL + n] = acc[i][j][r];
                    }
                }
            }
        }
    }
}

// ---------------------------------------------------------------------------
// MFMA sliding-window attention (unchanged — validated incl. post-timing).
// Block: 4 waves, 64 queries (wave w owns 16). Key tile: 192 kv.
// Qp, Kp: bf16 (BH, LQ, 64); Vt: bf16 (BH, 64, LQ); O: bf16 (B, LQ, 512).
// Register staging with swizzled ds_write; zero-fill out-of-window tiles.
// ---------------------------------------------------------------------------
__global__ __launch_bounds__(256) void attn_mfma(
    const unsigned short* __restrict__ Qp, const unsigned short* __restrict__ Kp,
    const unsigned short* __restrict__ Vt, unsigned short* __restrict__ O)
{
    __shared__ __align__(16) unsigned short Ks[192 * 64];   // 24576 B, XOR-swizzled
    __shared__ __align__(16) unsigned short Vs[64 * 192];   // 24576 B, XOR-swizzled
    __shared__ __align__(16) unsigned short Ps[64 * 200];   // 25600 B, padded rows

    const int tid = threadIdx.x;
    const int lane = tid & 63;
    const int w = tid >> 6;
    const int bh = blockIdx.y;
    const int j0 = blockIdx.x * 64;
    const int kv0 = j0 - 128;

    const unsigned short* Kg = Kp + (size_t)bh * LQ * DHEAD;
    const unsigned short* Vg = Vt + (size_t)bh * DHEAD * LQ;

    const us8 zz = {0, 0, 0, 0, 0, 0, 0, 0};

    // ---- load K tile [192 rows][64] to registers (6 x 16B chunks/thread) ----
    us8 kreg[6];
    #pragma unroll
    for (int i = 0; i < 6; ++i) {
        int c = i * 256 + tid;              // chunk 0..1535
        int row = c >> 3, g = c & 7;
        int grow = kv0 + row;
        us8 t = zz;
        if (grow >= 0) t = *(const us8*)&Kg[(size_t)grow * DHEAD + g * 8];
        kreg[i] = t;
    }
    // ---- load V^T tile [64 d][192 kv] to registers ----
    us8 vreg[6];
    #pragma unroll
    for (int i = 0; i < 6; ++i) {
        int c = i * 256 + tid;
        int d = c / 24, g = c - d * 24;     // g: kv-chunk 0..23
        int col = kv0 + g * 8;              // kv0 is 8-aligned -> chunk fully in/out
        us8 t = zz;
        if (col >= 0) t = *(const us8*)&Vg[(size_t)d * LQ + col];
        vreg[i] = t;
    }
    // ---- ds_write with XOR swizzle ----
    #pragma unroll
    for (int i = 0; i < 6; ++i) {
        int c = i * 256 + tid;
        int row = c >> 3, g = c & 7;
        *(us8*)&Ks[row * 64 + ((g ^ (row & 7)) << 3)] = kreg[i];
    }
    #pragma unroll
    for (int i = 0; i < 6; ++i) {
        int c = i * 256 + tid;
        int d = c / 24, g = c - d * 24;
        int sg = (g & ~7) | ((g & 7) ^ (d & 7));
        *(us8*)&Vs[d * 192 + sg * 8] = vreg[i];
    }

    const int frow = lane & 15, fkg = lane >> 4;

    // ---- Q fragments straight from global ----
    bf16x8 qa[2];
    {
        const unsigned short* Qrow = Qp + ((size_t)bh * LQ + j0 + w * 16 + frow) * DHEAD;
        qa[0] = *(const bf16x8*)&Qrow[fkg * 8];
        qa[1] = *(const bf16x8*)&Qrow[32 + fkg * 8];
    }

    __syncthreads();   // staging complete

    // ---- S = Q K^T over 12 kv blocks ----
    f32x4 sacc[12];
    #pragma unroll
    for (int b = 0; b < 12; ++b) sacc[b] = f32x4{0.f, 0.f, 0.f, 0.f};
    #pragma unroll
    for (int b = 0; b < 12; ++b) {
        #pragma unroll
        for (int ks = 0; ks < 2; ++ks) {
            int row = b * 16 + frow;
            int kg = ks * 4 + fkg;
            bf16x8 kb = *(const bf16x8*)&Ks[row * 64 + ((kg ^ (row & 7)) << 3)];
            sacc[b] = __builtin_amdgcn_mfma_f32_16x16x32_bf16(qa[ks], kb, sacc[b], 0, 0, 0);
        }
    }

    // ---- mask + softmax (row = query, spread over 16 lanes x 12 regs) ----
    #pragma unroll
    for (int r = 0; r < 4; ++r) {
        int q = w * 16 + fkg * 4 + r;          // query within 64-tile
        float sv[12];
        float mx = -1e30f;
        #pragma unroll
        for (int b = 0; b < 12; ++b) {
            int rel = b * 16 + frow - 128 - q;          // kv - j
            int kvabs = kv0 + b * 16 + frow;
            bool valid = (rel <= 0) & (rel >= -(SPAN - 1)) & (kvabs >= 0);
            float s = valid ? sacc[b][r] * 0.125f : -1e30f;
            sv[b] = s;
            mx = fmaxf(mx, s);
        }
        #pragma unroll
        for (int off = 1; off < 16; off <<= 1) mx = fmaxf(mx, __shfl_xor(mx, off));
        float sum = 0.f;
        #pragma unroll
        for (int b = 0; b < 12; ++b) { float p = __expf(sv[b] - mx); sv[b] = p; sum += p; }
        #pragma unroll
        for (int off = 1; off < 16; off <<= 1) sum += __shfl_xor(sum, off);
        float inv = 1.0f / sum;
        #pragma unroll
        for (int b = 0; b < 12; ++b) sacc[b][r] = sv[b] * inv;
    }

    // ---- P -> bf16 into its own LDS buffer (wave-private rows) ----
    #pragma unroll
    for (int b = 0; b < 12; ++b) {
        #pragma unroll
        for (int r = 0; r < 4; ++r) {
            int q = w * 16 + fkg * 4 + r;
            Ps[q * 200 + b * 16 + frow] = f2bf(sacc[b][r]);
        }
    }
    // no barrier needed: each wave reads only its own 16 Ps rows (lgkm-ordered)

    // ---- O = P V ----
    f32x4 oacc[4];
    #pragma unroll
    for (int nb = 0; nb < 4; ++nb) oacc[nb] = f32x4{0.f, 0.f, 0.f, 0.f};
    #pragma unroll
    for (int kb = 0; kb < 6; ++kb) {
        int q = w * 16 + frow;
        bf16x8 pa = *(const bf16x8*)&Ps[q * 200 + (kb * 4 + fkg) * 8];
        #pragma unroll
        for (int nb = 0; nb < 4; ++nb) {
            int d = nb * 16 + frow;
            int g = kb * 4 + fkg;
            int sg = (g & ~7) | ((g & 7) ^ (d & 7));
            bf16x8 vb = *(const bf16x8*)&Vs[d * 192 + sg * 8];
            oacc[nb] = __builtin_amdgcn_mfma_f32_16x16x32_bf16(pa, vb, oacc[nb], 0, 0, 0);
        }
    }

    // ---- write O (B, LQ, 512) bf16 ----
    int b = bh >> 3, h = bh & 7;
    #pragma unroll
    for (int nb = 0; nb < 4; ++nb) {
        #pragma unroll
        for (int r = 0; r < 4; ++r) {
            int jq = j0 + w * 16 + fkg * 4 + r;
            int col = h * 64 + nb * 16 + frow;
            O[(size_t)(b * LQ + jq) * DMODEL + col] = f2bf(oacc[nb][r]);
        }
    }
}

// ---------------------------------------------------------------------------
extern "C" void kernel_launch(void* const* d_in, const int* in_sizes, int n_in,
                              void* d_out, int out_size, void* d_ws, size_t ws_size,
                              hipStream_t stream) {
    const float* q  = (const float*)d_in[0];
    const float* k  = (const float*)d_in[1];
    const float* v  = (const float*)d_in[2];
    const float* Wq = (const float*)d_in[3];
    const float* Wk = (const float*)d_in[4];
    const float* Wv = (const float*)d_in[5];
    const float* Wo = (const float*)d_in[6];

    const size_t MK = (size_t)MROWS * DMODEL;   // 1M elems
    const size_t WK = (size_t)DMODEL * DMODEL;  // 256K elems

    unsigned short* WtQ = (unsigned short*)d_ws;
    unsigned short* WtK = WtQ + WK;
    unsigned short* WtV = WtK + WK;
    unsigned short* WtO = WtV + WK;
    unsigned short* Qp  = WtO + WK;
    unsigned short* Kp  = Qp + MK;
    unsigned short* Vt  = Kp + MK;
    unsigned short* Ah  = Vt + MK;

    transposeW<<<dim3(8, 8, 4), 256, 0, stream>>>(Wq, Wk, Wv, Wo, WtQ, WtK, WtV, WtO);

    // Q + K projections fused in one launch (z selects); V separate (mode 2).
    gemm_direct<1, true><<<dim3(8, 32, 2), 256, 0, stream>>>(q, k, WtQ, WtK, Qp, Kp);
    gemm_direct<2, true><<<dim3(8, 32, 1), 256, 0, stream>>>(v, v, WtV, WtV, Vt, Vt);

    attn_mfma<<<dim3(LQ / 64, 16), 256, 0, stream>>>(Qp, Kp, Vt, Ah);

    gemm_direct<0, false><<<dim3(8, 32, 1), 256, 0, stream>>>(Ah, Ah, WtO, WtO, d_out, d_out);
}

// Round 6
// 42.778 us; speedup vs baseline: 1.5833x; 1.5833x over previous
//
#include <hip/hip_runtime.h>
#include <hip/hip_bf16.h>

// B=2, LQ=LKV=1024, H=8, DQK=DV=64, DQ=DK=DVIN=DOUT=512, SPAN=128, STRIDE=1
#define LQ 1024
#define NH 8
#define DHEAD 64
#define DMODEL 512
#define SPAN 128
#define MROWS 2048   // B*LQ

typedef __attribute__((ext_vector_type(8))) short   bf16x8;
typedef __attribute__((ext_vector_type(4))) float   f32x4;
typedef __attribute__((ext_vector_type(8))) unsigned short us8;

static __device__ __forceinline__ unsigned short f2bf(float f) {
    union { __hip_bfloat16 h; unsigned short u; } cv;
    cv.h = __float2bfloat16(f);
    return cv.u;
}

static __device__ __forceinline__ void gload_lds16(const void* g, void* l) {
    __builtin_amdgcn_global_load_lds((const __attribute__((address_space(1))) void*)g,
                                     (__attribute__((address_space(3))) void*)l, 16, 0, 0);
}

// ---------------------------------------------------------------------------
// Prep: transpose+cast weights: Wt[n][k] = bf16(W[k][n]), 512x512 each
// (unchanged — validated)
// ---------------------------------------------------------------------------
__global__ __launch_bounds__(256) void transposeW(
    const float* __restrict__ W0, const float* __restrict__ W1,
    const float* __restrict__ W2, const float* __restrict__ W3,
    unsigned short* __restrict__ T0, unsigned short* __restrict__ T1,
    unsigned short* __restrict__ T2, unsigned short* __restrict__ T3)
{
    const float* W = blockIdx.z == 0 ? W0 : blockIdx.z == 1 ? W1 : blockIdx.z == 2 ? W2 : W3;
    unsigned short* T = blockIdx.z == 0 ? T0 : blockIdx.z == 1 ? T1 : blockIdx.z == 2 ? T2 : T3;
    __shared__ unsigned short sT[64][72];
    int c = threadIdx.x & 63;
    int r0 = (threadIdx.x >> 6) * 16;
    int n0 = blockIdx.x * 64, k0 = blockIdx.y * 64;
    #pragma unroll
    for (int i = 0; i < 16; ++i) {
        int r = r0 + i;
        sT[c][r] = f2bf(W[(size_t)(k0 + r) * DMODEL + n0 + c]);
    }
    __syncthreads();
    #pragma unroll
    for (int i = 0; i < 16; ++i) {
        int r = r0 + i;
        T[(size_t)(n0 + r) * DMODEL + k0 + c] = sT[r][c];
    }
}

// ---------------------------------------------------------------------------
// Fused Q/K/V projection GEMM (blockIdx.z selects input/weight/output).
// C[2048][512] = bf16(A_f32[2048][512]) @ W; Bt = W^T bf16 [N][K].
// Tile 64x64, BK=64, 4 waves (2x2), double-buffered LDS.
// A staged via registers (f32 load -> cvt -> swizzled ds_write_b128) —
// the cast kernel is fused away. B staged via global_load_lds (validated).
// z=0,1 (Q,K): scatter bf16 to (B,H,LQ,64).  z=2 (V): swapped operands,
// write C^T bf16 to (B,H,64,LQ).
// ---------------------------------------------------------------------------
__global__ __launch_bounds__(256) void gemm_qkv(
    const float* __restrict__ q, const float* __restrict__ k, const float* __restrict__ v,
    const unsigned short* __restrict__ WtQ, const unsigned short* __restrict__ WtK,
    const unsigned short* __restrict__ WtV,
    unsigned short* __restrict__ Qp, unsigned short* __restrict__ Kp,
    unsigned short* __restrict__ Vt)
{
    __shared__ unsigned short As[2][4096];   // 64 rows x 64 k, swizzled
    __shared__ unsigned short Bs[2][4096];

    const int z = blockIdx.z;
    const float* A = z == 0 ? q : (z == 1 ? k : v);
    const unsigned short* Bt = z == 0 ? WtQ : (z == 1 ? WtK : WtV);
    unsigned short* C = z == 0 ? Qp : (z == 1 ? Kp : Vt);
    const bool mode2 = (z == 2);

    const int tid = threadIdx.x;
    const int lane = tid & 63;
    const int w = tid >> 6;
    const int wm = w >> 1, wn = w & 1;
    const int m0 = blockIdx.y * 64;
    const int n0 = blockIdx.x * 64;

    // B staging (global_load_lds, pre-swizzled source) — round-2 validated
    const int srow = lane >> 3;
    const int sgrp = (lane & 7) ^ srow;

    f32x4 acc[2][2];
    #pragma unroll
    for (int i = 0; i < 2; ++i)
        #pragma unroll
        for (int j = 0; j < 2; ++j)
            acc[i][j] = f32x4{0.f, 0.f, 0.f, 0.f};

    auto stageB = [&](int buf, int kt) {
        const int k0 = kt * 64;
        #pragma unroll
        for (int cc = 0; cc < 2; ++cc) {
            int call = w * 2 + cc;
            int row = call * 8 + srow;
            gload_lds16(Bt + (size_t)(n0 + row) * DMODEL + k0 + (sgrp << 3),
                        &Bs[buf][call * 512]);
        }
    };

    // A staging: thread covers chunks c = i*256+tid (i=0,1);
    // chunk c: row = c>>3, g = c&7 -> 8 f32 from A[(m0+row)*512 + k0 + g*8]
    float4 areg[2][2];
    auto loadA = [&](int kt) {
        const int k0 = kt * 64;
        #pragma unroll
        for (int i = 0; i < 2; ++i) {
            int c = i * 256 + tid;
            int row = c >> 3, g = c & 7;
            const float* p = A + (size_t)(m0 + row) * DMODEL + k0 + g * 8;
            areg[i][0] = *(const float4*)p;
            areg[i][1] = *(const float4*)(p + 4);
        }
    };
    auto writeA = [&](int buf) {
        #pragma unroll
        for (int i = 0; i < 2; ++i) {
            int c = i * 256 + tid;
            int row = c >> 3, g = c & 7;
            us8 t;
            t[0] = f2bf(areg[i][0].x); t[1] = f2bf(areg[i][0].y);
            t[2] = f2bf(areg[i][0].z); t[3] = f2bf(areg[i][0].w);
            t[4] = f2bf(areg[i][1].x); t[5] = f2bf(areg[i][1].y);
            t[6] = f2bf(areg[i][1].z); t[7] = f2bf(areg[i][1].w);
            *(us8*)&As[buf][row * 64 + ((g ^ (row & 7)) << 3)] = t;
        }
    };

    const int frow = lane & 15;
    const int fkg  = lane >> 4;

    auto ldfrag = [&](const unsigned short* base, int rb, int ks) -> bf16x8 {
        int row = rb * 16 + frow;
        int kg = ks * 4 + fkg;
        int off = row * 64 + ((kg ^ (row & 7)) << 3);
        return *(const bf16x8*)&base[off];
    };

    // operand-role select (wave-uniform): mode2 swaps A<->B fragments
    const unsigned short* aB[2] = { mode2 ? Bs[0] : As[0], mode2 ? Bs[1] : As[1] };
    const unsigned short* bB[2] = { mode2 ? As[0] : Bs[0], mode2 ? As[1] : Bs[1] };
    const int ra = mode2 ? wn : wm;
    const int rb_ = mode2 ? wm : wn;

    loadA(0);
    stageB(0, 0);
    writeA(0);
    __syncthreads();

    for (int kt = 0; kt < 8; ++kt) {
        int buf = kt & 1;
        if (kt < 7) { loadA(kt + 1); stageB(buf ^ 1, kt + 1); }
        #pragma unroll
        for (int ks = 0; ks < 2; ++ks) {
            bf16x8 a0 = ldfrag(aB[buf], ra * 2 + 0, ks);
            bf16x8 a1 = ldfrag(aB[buf], ra * 2 + 1, ks);
            bf16x8 b0 = ldfrag(bB[buf], rb_ * 2 + 0, ks);
            bf16x8 b1 = ldfrag(bB[buf], rb_ * 2 + 1, ks);
            acc[0][0] = __builtin_amdgcn_mfma_f32_16x16x32_bf16(a0, b0, acc[0][0], 0, 0, 0);
            acc[0][1] = __builtin_amdgcn_mfma_f32_16x16x32_bf16(a0, b1, acc[0][1], 0, 0, 0);
            acc[1][0] = __builtin_amdgcn_mfma_f32_16x16x32_bf16(a1, b0, acc[1][0], 0, 0, 0);
            acc[1][1] = __builtin_amdgcn_mfma_f32_16x16x32_bf16(a1, b1, acc[1][1], 0, 0, 0);
        }
        if (kt < 7) writeA(buf ^ 1);
        __syncthreads();
    }

    // C/D layout: col = lane&15, row = (lane>>4)*4 + r   [m89-verified]
    #pragma unroll
    for (int i = 0; i < 2; ++i) {
        #pragma unroll
        for (int j = 0; j < 2; ++j) {
            #pragma unroll
            for (int r = 0; r < 4; ++r) {
                if (mode2) {
                    // acc rows = n-dim (i), cols = m-dim (j)
                    int n = n0 + wn * 32 + i * 16 + (lane >> 4) * 4 + r;
                    int m = m0 + wm * 32 + j * 16 + (lane & 15);
                    int b = m >> 10, jq = m & 1023, h = n >> 6, d = n & 63;
                    C[(((size_t)(b * NH + h) * DHEAD) + d) * LQ + jq] = f2bf(acc[i][j][r]);
                } else {
                    int m = m0 + wm * 32 + i * 16 + (lane >> 4) * 4 + r;
                    int n = n0 + wn * 32 + j * 16 + (lane & 15);
                    int b = m >> 10, jq = m & 1023, h = n >> 6, d = n & 63;
                    C[(((size_t)(b * NH + h) * LQ) + jq) * DHEAD + d] = f2bf(acc[i][j][r]);
                }
            }
        }
    }
}

// ---------------------------------------------------------------------------
// bf16 MFMA GEMM for the output projection (round-2 validated, MODE 0 only):
// C_f32[2048][512] = A_bf16[2048][512] @ W; Bt = W^T bf16 [N][K].
// ---------------------------------------------------------------------------
__global__ __launch_bounds__(256) void gemm_out(
    const unsigned short* __restrict__ A, const unsigned short* __restrict__ Bt,
    float* __restrict__ C)
{
    __shared__ unsigned short As[2][4096];
    __shared__ unsigned short Bs[2][4096];

    const int tid = threadIdx.x;
    const int lane = tid & 63;
    const int w = tid >> 6;
    const int wm = w >> 1, wn = w & 1;
    const int m0 = blockIdx.y * 64;
    const int n0 = blockIdx.x * 64;

    const int srow = lane >> 3;
    const int sgrp = (lane & 7) ^ srow;

    f32x4 acc[2][2];
    #pragma unroll
    for (int i = 0; i < 2; ++i)
        #pragma unroll
        for (int j = 0; j < 2; ++j)
            acc[i][j] = f32x4{0.f, 0.f, 0.f, 0.f};

    auto stage = [&](int buf, int kt) {
        const int k0 = kt * 64;
        #pragma unroll
        for (int cc = 0; cc < 2; ++cc) {
            int call = w * 2 + cc;
            int row = call * 8 + srow;
            gload_lds16(A + (size_t)(m0 + row) * DMODEL + k0 + (sgrp << 3), &As[buf][call * 512]);
            gload_lds16(Bt + (size_t)(n0 + row) * DMODEL + k0 + (sgrp << 3), &Bs[buf][call * 512]);
        }
    };

    const int frow = lane & 15;
    const int fkg  = lane >> 4;

    auto ldfrag = [&](const unsigned short* base, int rb, int ks) -> bf16x8 {
        int row = rb * 16 + frow;
        int kg = ks * 4 + fkg;
        int off = row * 64 + ((kg ^ (row & 7)) << 3);
        return *(const bf16x8*)&base[off];
    };

    stage(0, 0);
    __syncthreads();

    for (int kt = 0; kt < 8; ++kt) {
        int buf = kt & 1;
        if (kt < 7) stage(buf ^ 1, kt + 1);
        #pragma unroll
        for (int ks = 0; ks < 2; ++ks) {
            bf16x8 a0 = ldfrag(As[buf], wm * 2 + 0, ks);
            bf16x8 a1 = ldfrag(As[buf], wm * 2 + 1, ks);
            bf16x8 b0 = ldfrag(Bs[buf], wn * 2 + 0, ks);
            bf16x8 b1 = ldfrag(Bs[buf], wn * 2 + 1, ks);
            acc[0][0] = __builtin_amdgcn_mfma_f32_16x16x32_bf16(a0, b0, acc[0][0], 0, 0, 0);
            acc[0][1] = __builtin_amdgcn_mfma_f32_16x16x32_bf16(a0, b1, acc[0][1], 0, 0, 0);
            acc[1][0] = __builtin_amdgcn_mfma_f32_16x16x32_bf16(a1, b0, acc[1][0], 0, 0, 0);
            acc[1][1] = __builtin_amdgcn_mfma_f32_16x16x32_bf16(a1, b1, acc[1][1], 0, 0, 0);
        }
        __syncthreads();
    }

    #pragma unroll
    for (int i = 0; i < 2; ++i) {
        #pragma unroll
        for (int j = 0; j < 2; ++j) {
            #pragma unroll
            for (int r = 0; r < 4; ++r) {
                int m = m0 + wm * 32 + i * 16 + (lane >> 4) * 4 + r;
                int n = n0 + wn * 32 + j * 16 + (lane & 15);
                C[(size_t)m * DMODEL + n] = acc[i][j][r];
            }
        }
    }
}

// ---------------------------------------------------------------------------
// MFMA sliding-window attention (unchanged — validated incl. post-timing).
// Block: 4 waves, 64 queries (wave w owns 16). Key tile: 192 kv.
// Qp, Kp: bf16 (BH, LQ, 64); Vt: bf16 (BH, 64, LQ); O: bf16 (B, LQ, 512).
// Register staging with swizzled ds_write; zero-fill out-of-window tiles.
// ---------------------------------------------------------------------------
__global__ __launch_bounds__(256) void attn_mfma(
    const unsigned short* __restrict__ Qp, const unsigned short* __restrict__ Kp,
    const unsigned short* __restrict__ Vt, unsigned short* __restrict__ O)
{
    __shared__ __align__(16) unsigned short Ks[192 * 64];   // 24576 B, XOR-swizzled
    __shared__ __align__(16) unsigned short Vs[64 * 192];   // 24576 B, XOR-swizzled
    __shared__ __align__(16) unsigned short Ps[64 * 200];   // 25600 B, padded rows

    const int tid = threadIdx.x;
    const int lane = tid & 63;
    const int w = tid >> 6;
    const int bh = blockIdx.y;
    const int j0 = blockIdx.x * 64;
    const int kv0 = j0 - 128;

    const unsigned short* Kg = Kp + (size_t)bh * LQ * DHEAD;
    const unsigned short* Vg = Vt + (size_t)bh * DHEAD * LQ;

    const us8 zz = {0, 0, 0, 0, 0, 0, 0, 0};

    us8 kreg[6];
    #pragma unroll
    for (int i = 0; i < 6; ++i) {
        int c = i * 256 + tid;
        int row = c >> 3, g = c & 7;
        int grow = kv0 + row;
        us8 t = zz;
        if (grow >= 0) t = *(const us8*)&Kg[(size_t)grow * DHEAD + g * 8];
        kreg[i] = t;
    }
    us8 vreg[6];
    #pragma unroll
    for (int i = 0; i < 6; ++i) {
        int c = i * 256 + tid;
        int d = c / 24, g = c - d * 24;
        int col = kv0 + g * 8;
        us8 t = zz;
        if (col >= 0) t = *(const us8*)&Vg[(size_t)d * LQ + col];
        vreg[i] = t;
    }
    #pragma unroll
    for (int i = 0; i < 6; ++i) {
        int c = i * 256 + tid;
        int row = c >> 3, g = c & 7;
        *(us8*)&Ks[row * 64 + ((g ^ (row & 7)) << 3)] = kreg[i];
    }
    #pragma unroll
    for (int i = 0; i < 6; ++i) {
        int c = i * 256 + tid;
        int d = c / 24, g = c - d * 24;
        int sg = (g & ~7) | ((g & 7) ^ (d & 7));
        *(us8*)&Vs[d * 192 + sg * 8] = vreg[i];
    }

    const int frow = lane & 15, fkg = lane >> 4;

    bf16x8 qa[2];
    {
        const unsigned short* Qrow = Qp + ((size_t)bh * LQ + j0 + w * 16 + frow) * DHEAD;
        qa[0] = *(const bf16x8*)&Qrow[fkg * 8];
        qa[1] = *(const bf16x8*)&Qrow[32 + fkg * 8];
    }

    __syncthreads();

    f32x4 sacc[12];
    #pragma unroll
    for (int b = 0; b < 12; ++b) sacc[b] = f32x4{0.f, 0.f, 0.f, 0.f};
    #pragma unroll
    for (int b = 0; b < 12; ++b) {
        #pragma unroll
        for (int ks = 0; ks < 2; ++ks) {
            int row = b * 16 + frow;
            int kg = ks * 4 + fkg;
            bf16x8 kb = *(const bf16x8*)&Ks[row * 64 + ((kg ^ (row & 7)) << 3)];
            sacc[b] = __builtin_amdgcn_mfma_f32_16x16x32_bf16(qa[ks], kb, sacc[b], 0, 0, 0);
        }
    }

    #pragma unroll
    for (int r = 0; r < 4; ++r) {
        int q = w * 16 + fkg * 4 + r;
        float sv[12];
        float mx = -1e30f;
        #pragma unroll
        for (int b = 0; b < 12; ++b) {
            int rel = b * 16 + frow - 128 - q;
            int kvabs = kv0 + b * 16 + frow;
            bool valid = (rel <= 0) & (rel >= -(SPAN - 1)) & (kvabs >= 0);
            float s = valid ? sacc[b][r] * 0.125f : -1e30f;
            sv[b] = s;
            mx = fmaxf(mx, s);
        }
        #pragma unroll
        for (int off = 1; off < 16; off <<= 1) mx = fmaxf(mx, __shfl_xor(mx, off));
        float sum = 0.f;
        #pragma unroll
        for (int b = 0; b < 12; ++b) { float p = __expf(sv[b] - mx); sv[b] = p; sum += p; }
        #pragma unroll
        for (int off = 1; off < 16; off <<= 1) sum += __shfl_xor(sum, off);
        float inv = 1.0f / sum;
        #pragma unroll
        for (int b = 0; b < 12; ++b) sacc[b][r] = sv[b] * inv;
    }

    #pragma unroll
    for (int b = 0; b < 12; ++b) {
        #pragma unroll
        for (int r = 0; r < 4; ++r) {
            int q = w * 16 + fkg * 4 + r;
            Ps[q * 200 + b * 16 + frow] = f2bf(sacc[b][r]);
        }
    }

    f32x4 oacc[4];
    #pragma unroll
    for (int nb = 0; nb < 4; ++nb) oacc[nb] = f32x4{0.f, 0.f, 0.f, 0.f};
    #pragma unroll
    for (int kb = 0; kb < 6; ++kb) {
        int q = w * 16 + frow;
        bf16x8 pa = *(const bf16x8*)&Ps[q * 200 + (kb * 4 + fkg) * 8];
        #pragma unroll
        for (int nb = 0; nb < 4; ++nb) {
            int d = nb * 16 + frow;
            int g = kb * 4 + fkg;
            int sg = (g & ~7) | ((g & 7) ^ (d & 7));
            bf16x8 vb = *(const bf16x8*)&Vs[d * 192 + sg * 8];
            oacc[nb] = __builtin_amdgcn_mfma_f32_16x16x32_bf16(pa, vb, oacc[nb], 0, 0, 0);
        }
    }

    int b = bh >> 3, h = bh & 7;
    #pragma unroll
    for (int nb = 0; nb < 4; ++nb) {
        #pragma unroll
        for (int r = 0; r < 4; ++r) {
            int jq = j0 + w * 16 + fkg * 4 + r;
            int col = h * 64 + nb * 16 + frow;
            O[(size_t)(b * LQ + jq) * DMODEL + col] = f2bf(oacc[nb][r]);
        }
    }
}

// ---------------------------------------------------------------------------
extern "C" void kernel_launch(void* const* d_in, const int* in_sizes, int n_in,
                              void* d_out, int out_size, void* d_ws, size_t ws_size,
                              hipStream_t stream) {
    const float* q  = (const float*)d_in[0];
    const float* k  = (const float*)d_in[1];
    const float* v  = (const float*)d_in[2];
    const float* Wq = (const float*)d_in[3];
    const float* Wk = (const float*)d_in[4];
    const float* Wv = (const float*)d_in[5];
    const float* Wo = (const float*)d_in[6];

    const size_t MK = (size_t)MROWS * DMODEL;   // 1M elems
    const size_t WK = (size_t)DMODEL * DMODEL;  // 256K elems

    unsigned short* WtQ = (unsigned short*)d_ws;
    unsigned short* WtK = WtQ + WK;
    unsigned short* WtV = WtK + WK;
    unsigned short* WtO = WtV + WK;
    unsigned short* Qp  = WtO + WK;
    unsigned short* Kp  = Qp + MK;
    unsigned short* Vt  = Kp + MK;
    unsigned short* Ah  = Vt + MK;

    transposeW<<<dim3(8, 8, 4), 256, 0, stream>>>(Wq, Wk, Wv, Wo, WtQ, WtK, WtV, WtO);

    // Q, K, V projections fused: 768 blocks = 3 blocks/CU co-resident.
    gemm_qkv<<<dim3(8, 32, 3), 256, 0, stream>>>(q, k, v, WtQ, WtK, WtV, Qp, Kp, Vt);

    attn_mfma<<<dim3(LQ / 64, 16), 256, 0, stream>>>(Qp, Kp, Vt, Ah);

    gemm_out<<<dim3(8, 32), 256, 0, stream>>>(Ah, WtO, (float*)d_out);
}

// Round 7
// 42.258 us; speedup vs baseline: 1.6028x; 1.0123x over previous
//
#include <hip/hip_runtime.h>
#include <hip/hip_bf16.h>

// B=2, LQ=LKV=1024, H=8, DQK=DV=64, DQ=DK=DVIN=DOUT=512, SPAN=128, STRIDE=1
#define LQ 1024
#define NH 8
#define DHEAD 64
#define DMODEL 512
#define SPAN 128
#define MROWS 2048   // B*LQ

typedef __attribute__((ext_vector_type(8))) short   bf16x8;
typedef __attribute__((ext_vector_type(4))) float   f32x4;
typedef __attribute__((ext_vector_type(8))) unsigned short us8;

static __device__ __forceinline__ unsigned short f2bf(float f) {
    union { __hip_bfloat16 h; unsigned short u; } cv;
    cv.h = __float2bfloat16(f);
    return cv.u;
}

static __device__ __forceinline__ void gload_lds16(const void* g, void* l) {
    __builtin_amdgcn_global_load_lds((const __attribute__((address_space(1))) void*)g,
                                     (__attribute__((address_space(3))) void*)l, 16, 0, 0);
}

// ---------------------------------------------------------------------------
// Prep: transpose+cast weights: Wt[n][k] = bf16(W[k][n]), 512x512 each
// (unchanged — validated)
// ---------------------------------------------------------------------------
__global__ __launch_bounds__(256) void transposeW(
    const float* __restrict__ W0, const float* __restrict__ W1,
    const float* __restrict__ W2, const float* __restrict__ W3,
    unsigned short* __restrict__ T0, unsigned short* __restrict__ T1,
    unsigned short* __restrict__ T2, unsigned short* __restrict__ T3)
{
    const float* W = blockIdx.z == 0 ? W0 : blockIdx.z == 1 ? W1 : blockIdx.z == 2 ? W2 : W3;
    unsigned short* T = blockIdx.z == 0 ? T0 : blockIdx.z == 1 ? T1 : blockIdx.z == 2 ? T2 : T3;
    __shared__ unsigned short sT[64][72];
    int c = threadIdx.x & 63;
    int r0 = (threadIdx.x >> 6) * 16;
    int n0 = blockIdx.x * 64, k0 = blockIdx.y * 64;
    #pragma unroll
    for (int i = 0; i < 16; ++i) {
        int r = r0 + i;
        sT[c][r] = f2bf(W[(size_t)(k0 + r) * DMODEL + n0 + c]);
    }
    __syncthreads();
    #pragma unroll
    for (int i = 0; i < 16; ++i) {
        int r = r0 + i;
        T[(size_t)(n0 + r) * DMODEL + k0 + c] = sT[r][c];
    }
}

// ---------------------------------------------------------------------------
// Fused Q/K/V projection GEMM (unchanged — validated round 6).
// ---------------------------------------------------------------------------
__global__ __launch_bounds__(256) void gemm_qkv(
    const float* __restrict__ q, const float* __restrict__ k, const float* __restrict__ v,
    const unsigned short* __restrict__ WtQ, const unsigned short* __restrict__ WtK,
    const unsigned short* __restrict__ WtV,
    unsigned short* __restrict__ Qp, unsigned short* __restrict__ Kp,
    unsigned short* __restrict__ Vt)
{
    __shared__ unsigned short As[2][4096];   // 64 rows x 64 k, swizzled
    __shared__ unsigned short Bs[2][4096];

    const int z = blockIdx.z;
    const float* A = z == 0 ? q : (z == 1 ? k : v);
    const unsigned short* Bt = z == 0 ? WtQ : (z == 1 ? WtK : WtV);
    unsigned short* C = z == 0 ? Qp : (z == 1 ? Kp : Vt);
    const bool mode2 = (z == 2);

    const int tid = threadIdx.x;
    const int lane = tid & 63;
    const int w = tid >> 6;
    const int wm = w >> 1, wn = w & 1;
    const int m0 = blockIdx.y * 64;
    const int n0 = blockIdx.x * 64;

    const int srow = lane >> 3;
    const int sgrp = (lane & 7) ^ srow;

    f32x4 acc[2][2];
    #pragma unroll
    for (int i = 0; i < 2; ++i)
        #pragma unroll
        for (int j = 0; j < 2; ++j)
            acc[i][j] = f32x4{0.f, 0.f, 0.f, 0.f};

    auto stageB = [&](int buf, int kt) {
        const int k0 = kt * 64;
        #pragma unroll
        for (int cc = 0; cc < 2; ++cc) {
            int call = w * 2 + cc;
            int row = call * 8 + srow;
            gload_lds16(Bt + (size_t)(n0 + row) * DMODEL + k0 + (sgrp << 3),
                        &Bs[buf][call * 512]);
        }
    };

    float4 areg[2][2];
    auto loadA = [&](int kt) {
        const int k0 = kt * 64;
        #pragma unroll
        for (int i = 0; i < 2; ++i) {
            int c = i * 256 + tid;
            int row = c >> 3, g = c & 7;
            const float* p = A + (size_t)(m0 + row) * DMODEL + k0 + g * 8;
            areg[i][0] = *(const float4*)p;
            areg[i][1] = *(const float4*)(p + 4);
        }
    };
    auto writeA = [&](int buf) {
        #pragma unroll
        for (int i = 0; i < 2; ++i) {
            int c = i * 256 + tid;
            int row = c >> 3, g = c & 7;
            us8 t;
            t[0] = f2bf(areg[i][0].x); t[1] = f2bf(areg[i][0].y);
            t[2] = f2bf(areg[i][0].z); t[3] = f2bf(areg[i][0].w);
            t[4] = f2bf(areg[i][1].x); t[5] = f2bf(areg[i][1].y);
            t[6] = f2bf(areg[i][1].z); t[7] = f2bf(areg[i][1].w);
            *(us8*)&As[buf][row * 64 + ((g ^ (row & 7)) << 3)] = t;
        }
    };

    const int frow = lane & 15;
    const int fkg  = lane >> 4;

    auto ldfrag = [&](const unsigned short* base, int rb, int ks) -> bf16x8 {
        int row = rb * 16 + frow;
        int kg = ks * 4 + fkg;
        int off = row * 64 + ((kg ^ (row & 7)) << 3);
        return *(const bf16x8*)&base[off];
    };

    const unsigned short* aB[2] = { mode2 ? Bs[0] : As[0], mode2 ? Bs[1] : As[1] };
    const unsigned short* bB[2] = { mode2 ? As[0] : Bs[0], mode2 ? As[1] : Bs[1] };
    const int ra = mode2 ? wn : wm;
    const int rb_ = mode2 ? wm : wn;

    loadA(0);
    stageB(0, 0);
    writeA(0);
    __syncthreads();

    for (int kt = 0; kt < 8; ++kt) {
        int buf = kt & 1;
        if (kt < 7) { loadA(kt + 1); stageB(buf ^ 1, kt + 1); }
        #pragma unroll
        for (int ks = 0; ks < 2; ++ks) {
            bf16x8 a0 = ldfrag(aB[buf], ra * 2 + 0, ks);
            bf16x8 a1 = ldfrag(aB[buf], ra * 2 + 1, ks);
            bf16x8 b0 = ldfrag(bB[buf], rb_ * 2 + 0, ks);
            bf16x8 b1 = ldfrag(bB[buf], rb_ * 2 + 1, ks);
            acc[0][0] = __builtin_amdgcn_mfma_f32_16x16x32_bf16(a0, b0, acc[0][0], 0, 0, 0);
            acc[0][1] = __builtin_amdgcn_mfma_f32_16x16x32_bf16(a0, b1, acc[0][1], 0, 0, 0);
            acc[1][0] = __builtin_amdgcn_mfma_f32_16x16x32_bf16(a1, b0, acc[1][0], 0, 0, 0);
            acc[1][1] = __builtin_amdgcn_mfma_f32_16x16x32_bf16(a1, b1, acc[1][1], 0, 0, 0);
        }
        if (kt < 7) writeA(buf ^ 1);
        __syncthreads();
    }

    #pragma unroll
    for (int i = 0; i < 2; ++i) {
        #pragma unroll
        for (int j = 0; j < 2; ++j) {
            #pragma unroll
            for (int r = 0; r < 4; ++r) {
                if (mode2) {
                    int n = n0 + wn * 32 + i * 16 + (lane >> 4) * 4 + r;
                    int m = m0 + wm * 32 + j * 16 + (lane & 15);
                    int b = m >> 10, jq = m & 1023, h = n >> 6, d = n & 63;
                    C[(((size_t)(b * NH + h) * DHEAD) + d) * LQ + jq] = f2bf(acc[i][j][r]);
                } else {
                    int m = m0 + wm * 32 + i * 16 + (lane >> 4) * 4 + r;
                    int n = n0 + wn * 32 + j * 16 + (lane & 15);
                    int b = m >> 10, jq = m & 1023, h = n >> 6, d = n & 63;
                    C[(((size_t)(b * NH + h) * LQ) + jq) * DHEAD + d] = f2bf(acc[i][j][r]);
                }
            }
        }
    }
}

// ---------------------------------------------------------------------------
// Output projection GEMM, re-tiled 32x64 for 2 blocks/CU co-residency:
// grid (8, 64) = 512 blocks. 4 waves; wave w computes 32x16 (n-slice w*16).
// Same swizzle/staging rules as the validated 64x64 kernel; A staged with
// ONE global_load_lds call/wave (rows w*8..w*8+8), B with two.
// ---------------------------------------------------------------------------
__global__ __launch_bounds__(256) void gemm_out(
    const unsigned short* __restrict__ A, const unsigned short* __restrict__ Bt,
    float* __restrict__ C)
{
    __shared__ unsigned short As[2][2048];   // 32 rows x 64 k, swizzled
    __shared__ unsigned short Bs[2][4096];   // 64 rows x 64 k, swizzled

    const int tid = threadIdx.x;
    const int lane = tid & 63;
    const int w = tid >> 6;
    const int m0 = blockIdx.y * 32;
    const int n0 = blockIdx.x * 64;

    const int srow = lane >> 3;
    const int sgrp = (lane & 7) ^ srow;

    f32x4 acc[2];
    acc[0] = f32x4{0.f, 0.f, 0.f, 0.f};
    acc[1] = f32x4{0.f, 0.f, 0.f, 0.f};

    auto stage = [&](int buf, int kt) {
        const int k0 = kt * 64;
        // A: one call per wave, rows w*8 .. w*8+8 (32 rows total)
        gload_lds16(A + (size_t)(m0 + w * 8 + srow) * DMODEL + k0 + (sgrp << 3),
                    &As[buf][w * 512]);
        // B: two calls per wave (64 rows total)
        #pragma unroll
        for (int cc = 0; cc < 2; ++cc) {
            int call = w * 2 + cc;
            int row = call * 8 + srow;
            gload_lds16(Bt + (size_t)(n0 + row) * DMODEL + k0 + (sgrp << 3),
                        &Bs[buf][call * 512]);
        }
    };

    const int frow = lane & 15;
    const int fkg  = lane >> 4;

    auto ldfrag = [&](const unsigned short* base, int rb, int ks) -> bf16x8 {
        int row = rb * 16 + frow;
        int kg = ks * 4 + fkg;
        int off = row * 64 + ((kg ^ (row & 7)) << 3);
        return *(const bf16x8*)&base[off];
    };

    stage(0, 0);
    __syncthreads();

    for (int kt = 0; kt < 8; ++kt) {
        int buf = kt & 1;
        if (kt < 7) stage(buf ^ 1, kt + 1);
        #pragma unroll
        for (int ks = 0; ks < 2; ++ks) {
            bf16x8 a0 = ldfrag(As[buf], 0, ks);
            bf16x8 a1 = ldfrag(As[buf], 1, ks);
            bf16x8 b0 = ldfrag(Bs[buf], w, ks);
            acc[0] = __builtin_amdgcn_mfma_f32_16x16x32_bf16(a0, b0, acc[0], 0, 0, 0);
            acc[1] = __builtin_amdgcn_mfma_f32_16x16x32_bf16(a1, b0, acc[1], 0, 0, 0);
        }
        __syncthreads();
    }

    #pragma unroll
    for (int i = 0; i < 2; ++i) {
        #pragma unroll
        for (int r = 0; r < 4; ++r) {
            int m = m0 + i * 16 + (lane >> 4) * 4 + r;
            int n = n0 + w * 16 + (lane & 15);
            C[(size_t)m * DMODEL + n] = acc[i][r];
        }
    }
}

// ---------------------------------------------------------------------------
// MFMA sliding-window attention (unchanged — validated incl. post-timing).
// ---------------------------------------------------------------------------
__global__ __launch_bounds__(256) void attn_mfma(
    const unsigned short* __restrict__ Qp, const unsigned short* __restrict__ Kp,
    const unsigned short* __restrict__ Vt, unsigned short* __restrict__ O)
{
    __shared__ __align__(16) unsigned short Ks[192 * 64];   // 24576 B, XOR-swizzled
    __shared__ __align__(16) unsigned short Vs[64 * 192];   // 24576 B, XOR-swizzled
    __shared__ __align__(16) unsigned short Ps[64 * 200];   // 25600 B, padded rows

    const int tid = threadIdx.x;
    const int lane = tid & 63;
    const int w = tid >> 6;
    const int bh = blockIdx.y;
    const int j0 = blockIdx.x * 64;
    const int kv0 = j0 - 128;

    const unsigned short* Kg = Kp + (size_t)bh * LQ * DHEAD;
    const unsigned short* Vg = Vt + (size_t)bh * DHEAD * LQ;

    const us8 zz = {0, 0, 0, 0, 0, 0, 0, 0};

    us8 kreg[6];
    #pragma unroll
    for (int i = 0; i < 6; ++i) {
        int c = i * 256 + tid;
        int row = c >> 3, g = c & 7;
        int grow = kv0 + row;
        us8 t = zz;
        if (grow >= 0) t = *(const us8*)&Kg[(size_t)grow * DHEAD + g * 8];
        kreg[i] = t;
    }
    us8 vreg[6];
    #pragma unroll
    for (int i = 0; i < 6; ++i) {
        int c = i * 256 + tid;
        int d = c / 24, g = c - d * 24;
        int col = kv0 + g * 8;
        us8 t = zz;
        if (col >= 0) t = *(const us8*)&Vg[(size_t)d * LQ + col];
        vreg[i] = t;
    }
    #pragma unroll
    for (int i = 0; i < 6; ++i) {
        int c = i * 256 + tid;
        int row = c >> 3, g = c & 7;
        *(us8*)&Ks[row * 64 + ((g ^ (row & 7)) << 3)] = kreg[i];
    }
    #pragma unroll
    for (int i = 0; i < 6; ++i) {
        int c = i * 256 + tid;
        int d = c / 24, g = c - d * 24;
        int sg = (g & ~7) | ((g & 7) ^ (d & 7));
        *(us8*)&Vs[d * 192 + sg * 8] = vreg[i];
    }

    const int frow = lane & 15, fkg = lane >> 4;

    bf16x8 qa[2];
    {
        const unsigned short* Qrow = Qp + ((size_t)bh * LQ + j0 + w * 16 + frow) * DHEAD;
        qa[0] = *(const bf16x8*)&Qrow[fkg * 8];
        qa[1] = *(const bf16x8*)&Qrow[32 + fkg * 8];
    }

    __syncthreads();

    f32x4 sacc[12];
    #pragma unroll
    for (int b = 0; b < 12; ++b) sacc[b] = f32x4{0.f, 0.f, 0.f, 0.f};
    #pragma unroll
    for (int b = 0; b < 12; ++b) {
        #pragma unroll
        for (int ks = 0; ks < 2; ++ks) {
            int row = b * 16 + frow;
            int kg = ks * 4 + fkg;
            bf16x8 kb = *(const bf16x8*)&Ks[row * 64 + ((kg ^ (row & 7)) << 3)];
            sacc[b] = __builtin_amdgcn_mfma_f32_16x16x32_bf16(qa[ks], kb, sacc[b], 0, 0, 0);
        }
    }

    #pragma unroll
    for (int r = 0; r < 4; ++r) {
        int q = w * 16 + fkg * 4 + r;
        float sv[12];
        float mx = -1e30f;
        #pragma unroll
        for (int b = 0; b < 12; ++b) {
            int rel = b * 16 + frow - 128 - q;
            int kvabs = kv0 + b * 16 + frow;
            bool valid = (rel <= 0) & (rel >= -(SPAN - 1)) & (kvabs >= 0);
            float s = valid ? sacc[b][r] * 0.125f : -1e30f;
            sv[b] = s;
            mx = fmaxf(mx, s);
        }
        #pragma unroll
        for (int off = 1; off < 16; off <<= 1) mx = fmaxf(mx, __shfl_xor(mx, off));
        float sum = 0.f;
        #pragma unroll
        for (int b = 0; b < 12; ++b) { float p = __expf(sv[b] - mx); sv[b] = p; sum += p; }
        #pragma unroll
        for (int off = 1; off < 16; off <<= 1) sum += __shfl_xor(sum, off);
        float inv = 1.0f / sum;
        #pragma unroll
        for (int b = 0; b < 12; ++b) sacc[b][r] = sv[b] * inv;
    }

    #pragma unroll
    for (int b = 0; b < 12; ++b) {
        #pragma unroll
        for (int r = 0; r < 4; ++r) {
            int q = w * 16 + fkg * 4 + r;
            Ps[q * 200 + b * 16 + frow] = f2bf(sacc[b][r]);
        }
    }

    f32x4 oacc[4];
    #pragma unroll
    for (int nb = 0; nb < 4; ++nb) oacc[nb] = f32x4{0.f, 0.f, 0.f, 0.f};
    #pragma unroll
    for (int kb = 0; kb < 6; ++kb) {
        int q = w * 16 + frow;
        bf16x8 pa = *(const bf16x8*)&Ps[q * 200 + (kb * 4 + fkg) * 8];
        #pragma unroll
        for (int nb = 0; nb < 4; ++nb) {
            int d = nb * 16 + frow;
            int g = kb * 4 + fkg;
            int sg = (g & ~7) | ((g & 7) ^ (d & 7));
            bf16x8 vb = *(const bf16x8*)&Vs[d * 192 + sg * 8];
            oacc[nb] = __builtin_amdgcn_mfma_f32_16x16x32_bf16(pa, vb, oacc[nb], 0, 0, 0);
        }
    }

    int b = bh >> 3, h = bh & 7;
    #pragma unroll
    for (int nb = 0; nb < 4; ++nb) {
        #pragma unroll
        for (int r = 0; r < 4; ++r) {
            int jq = j0 + w * 16 + fkg * 4 + r;
            int col = h * 64 + nb * 16 + frow;
            O[(size_t)(b * LQ + jq) * DMODEL + col] = f2bf(oacc[nb][r]);
        }
    }
}

// ---------------------------------------------------------------------------
extern "C" void kernel_launch(void* const* d_in, const int* in_sizes, int n_in,
                              void* d_out, int out_size, void* d_ws, size_t ws_size,
                              hipStream_t stream) {
    const float* q  = (const float*)d_in[0];
    const float* k  = (const float*)d_in[1];
    const float* v  = (const float*)d_in[2];
    const float* Wq = (const float*)d_in[3];
    const float* Wk = (const float*)d_in[4];
    const float* Wv = (const float*)d_in[5];
    const float* Wo = (const float*)d_in[6];

    const size_t MK = (size_t)MROWS * DMODEL;   // 1M elems
    const size_t WK = (size_t)DMODEL * DMODEL;  // 256K elems

    unsigned short* WtQ = (unsigned short*)d_ws;
    unsigned short* WtK = WtQ + WK;
    unsigned short* WtV = WtK + WK;
    unsigned short* WtO = WtV + WK;
    unsigned short* Qp  = WtO + WK;
    unsigned short* Kp  = Qp + MK;
    unsigned short* Vt  = Kp + MK;
    unsigned short* Ah  = Vt + MK;

    transposeW<<<dim3(8, 8, 4), 256, 0, stream>>>(Wq, Wk, Wv, Wo, WtQ, WtK, WtV, WtO);

    // Q, K, V projections fused: 768 blocks = 3 blocks/CU co-resident.
    gemm_qkv<<<dim3(8, 32, 3), 256, 0, stream>>>(q, k, v, WtQ, WtK, WtV, Qp, Kp, Vt);

    attn_mfma<<<dim3(LQ / 64, 16), 256, 0, stream>>>(Qp, Kp, Vt, Ah);

    // Output projection: 32x64 tiles -> 512 blocks = 2 blocks/CU.
    gemm_out<<<dim3(8, 64), 256, 0, stream>>>(Ah, WtO, (float*)d_out);
}